// Round 1
// baseline (1112.538 us; speedup 1.0000x reference)
//
#include <hip/hip_runtime.h>

#define NN 50000
#define NE 800000
#define NT 850000   // NE + NN self loops
#define NG 512

// ---------------- edge bucket sort (by dst) ----------------

__global__ void k_hist(const int* __restrict__ dst, int* __restrict__ cnt) {
  int i = blockIdx.x * blockDim.x + threadIdx.x;
  if (i < NT) {
    int d = (i < NE) ? dst[i] : (i - NE);
    atomicAdd(&cnt[d], 1);
  }
}

__global__ void k_scan(const int* __restrict__ cnt, int* __restrict__ offs) {
  __shared__ int sh[1024];
  int tid = threadIdx.x;
  int carry = 0;
  for (int base = 0; base < NN; base += 1024) {
    int i = base + tid;
    int v = (i < NN) ? cnt[i] : 0;
    sh[tid] = v;
    __syncthreads();
    for (int off = 1; off < 1024; off <<= 1) {
      int t = (tid >= off) ? sh[tid - off] : 0;
      __syncthreads();
      sh[tid] += t;
      __syncthreads();
    }
    if (i < NN) offs[i] = carry + sh[tid] - v;  // exclusive
    carry += sh[1023];
    __syncthreads();
  }
  if (tid == 0) offs[NN] = carry;
}

__global__ void k_scatter(const int* __restrict__ src, const int* __restrict__ dst,
                          const int* __restrict__ offs, int* __restrict__ cur,
                          int* __restrict__ srt) {
  int i = blockIdx.x * blockDim.x + threadIdx.x;
  if (i < NT) {
    int s, d;
    if (i < NE) { s = src[i]; d = dst[i]; }
    else        { s = d = i - NE; }
    int pos = offs[d] + atomicAdd(&cur[d], 1);
    srt[pos] = s;
  }
}

// ---------------- dual GEMM: C1 = A@W1^T + b1, C2 = A@W2^T + b2 ----------------
// A: [M,K] row-major; W: [FO,K] row-major; C: [M,FO]
// block tile 64x64, 256 threads, 4x4 micro-tile per thread, TK=16

__global__ __launch_bounds__(256)
void k_gemm_dual(const float* __restrict__ A, int M, int K, int FO,
                 const float* __restrict__ W1, const float* __restrict__ b1,
                 const float* __restrict__ W2, const float* __restrict__ b2,
                 float* __restrict__ C1, float* __restrict__ C2) {
  __shared__ float As[16][68];
  __shared__ float Bs1[16][68];
  __shared__ float Bs2[16][68];
  int tid = threadIdx.x;
  int tx = tid % 16, ty = tid / 16;
  int mb = blockIdx.x * 64, nb = blockIdx.y * 64;
  float acc1[4][4] = {{0}}, acc2[4][4] = {{0}};
  for (int k0 = 0; k0 < K; k0 += 16) {
    for (int t = tid; t < 64 * 16; t += 256) {
      int m = t / 16, k = t % 16;
      float v = 0.f;
      if (mb + m < M && k0 + k < K) v = A[(size_t)(mb + m) * K + k0 + k];
      As[k][m] = v;
    }
    for (int t = tid; t < 64 * 16; t += 256) {
      int n = t / 16, k = t % 16;
      float v1 = 0.f, v2 = 0.f;
      if (nb + n < FO && k0 + k < K) {
        v1 = W1[(size_t)(nb + n) * K + k0 + k];
        v2 = W2[(size_t)(nb + n) * K + k0 + k];
      }
      Bs1[k][n] = v1;
      Bs2[k][n] = v2;
    }
    __syncthreads();
#pragma unroll
    for (int k = 0; k < 16; ++k) {
      float a[4], p[4], q[4];
#pragma unroll
      for (int i = 0; i < 4; ++i) a[i] = As[k][ty * 4 + i];
#pragma unroll
      for (int j = 0; j < 4; ++j) { p[j] = Bs1[k][tx * 4 + j]; q[j] = Bs2[k][tx * 4 + j]; }
#pragma unroll
      for (int i = 0; i < 4; ++i)
#pragma unroll
        for (int j = 0; j < 4; ++j) {
          acc1[i][j] += a[i] * p[j];
          acc2[i][j] += a[i] * q[j];
        }
    }
    __syncthreads();
  }
#pragma unroll
  for (int i = 0; i < 4; ++i) {
    int m = mb + ty * 4 + i;
    if (m >= M) continue;
#pragma unroll
    for (int j = 0; j < 4; ++j) {
      int n = nb + tx * 4 + j;
      if (n >= FO) continue;
      C1[(size_t)m * FO + n] = acc1[i][j] + b1[n];
      C2[(size_t)m * FO + n] = acc2[i][j] + b2[n];
    }
  }
}

// ---------------- fused GAT edge phase: one wave per dst node ----------------
// lane l owns channel l of each head. Online softmax over incoming edges.

template <int H, int C, bool RELU>
__global__ __launch_bounds__(256)
void k_gat(const float* __restrict__ xl, const float* __restrict__ xr,
           const float* __restrict__ att, const float* __restrict__ bias,
           const int* __restrict__ offs, const int* __restrict__ srt,
           float* __restrict__ out) {
  constexpr int FO = H * C;
  int wave = threadIdx.x >> 6;
  int lane = threadIdx.x & 63;
  int n = blockIdx.x * 4 + wave;
  if (n >= NN) return;
  bool act = (lane < C);
  float xr_v[H], att_v[H], m[H], d[H], acc[H];
#pragma unroll
  for (int h = 0; h < H; ++h) {
    int idx = h * C + lane;
    xr_v[h] = act ? xr[(size_t)n * FO + idx] : 0.f;
    att_v[h] = act ? att[idx] : 0.f;
    m[h] = -1e30f;
    d[h] = 0.f;
    acc[h] = 0.f;
  }
  int e0 = offs[n], e1 = offs[n + 1];
  for (int j = e0; j < e1; ++j) {
    int s = srt[j];
    float xs[H], contrib[H];
#pragma unroll
    for (int h = 0; h < H; ++h) {
      xs[h] = act ? xl[(size_t)s * FO + h * C + lane] : 0.f;
      float t = xs[h] + xr_v[h];
      t = (t > 0.f) ? t : 0.2f * t;
      contrib[h] = t * att_v[h];
    }
#pragma unroll
    for (int off = 32; off > 0; off >>= 1) {
#pragma unroll
      for (int h = 0; h < H; ++h) contrib[h] += __shfl_xor(contrib[h], off, 64);
    }
#pragma unroll
    for (int h = 0; h < H; ++h) {
      float e = contrib[h];
      float nm = fmaxf(m[h], e);
      float scale = __expf(m[h] - nm);
      float pp = __expf(e - nm);
      d[h] = d[h] * scale + pp;
      acc[h] = acc[h] * scale + pp * xs[h];
      m[h] = nm;
    }
  }
#pragma unroll
  for (int h = 0; h < H; ++h) {
    if (act) {
      float v = acc[h] / d[h] + bias[h * C + lane];
      if (RELU) v = fmaxf(v, 0.f);
      out[(size_t)n * FO + h * C + lane] = v;
    }
  }
}

// ---------------- global add pool ----------------

__global__ void k_pool(const float* __restrict__ h, const int* __restrict__ batch,
                       float* __restrict__ out) {
  int i = blockIdx.x * blockDim.x + threadIdx.x;
  if (i < NN * 20) {
    int n = i / 20, k = i % 20;
    atomicAdd(&out[batch[n] * 20 + k], h[(size_t)n * 20 + k]);
  }
}

// ---------------- launch ----------------

extern "C" void kernel_launch(void* const* d_in, const int* in_sizes, int n_in,
                              void* d_out, int out_size, void* d_ws, size_t ws_size,
                              hipStream_t stream) {
  const float* x = (const float*)d_in[0];
  const int* src = (const int*)d_in[1];
  const int* dst = src + NE;
  const int* batch = (const int*)d_in[2];
  const float *Wl[4], *bl[4], *Wr[4], *br[4], *att[4], *bb[4];
  for (int li = 0; li < 4; ++li) {
    Wl[li]  = (const float*)d_in[3 + li * 6 + 0];
    bl[li]  = (const float*)d_in[3 + li * 6 + 1];
    Wr[li]  = (const float*)d_in[3 + li * 6 + 2];
    br[li]  = (const float*)d_in[3 + li * 6 + 3];
    att[li] = (const float*)d_in[3 + li * 6 + 4];
    bb[li]  = (const float*)d_in[3 + li * 6 + 5];
  }

  char* p = (char*)d_ws;
  auto alloc = [&](size_t bytes) {
    char* r = p;
    p += (bytes + 255) & ~(size_t)255;
    return r;
  };
  float* xl  = (float*)alloc((size_t)NN * 192 * 4);
  float* xr  = (float*)alloc((size_t)NN * 192 * 4);
  float* hb  = (float*)alloc((size_t)NN * 192 * 4);
  int* srt   = (int*)alloc((size_t)NT * 4);
  int* offs  = (int*)alloc((size_t)(NN + 1) * 4);
  int* cnt   = (int*)alloc((size_t)NN * 4);
  int* cur   = (int*)alloc((size_t)NN * 4);

  hipMemsetAsync(cnt, 0, (size_t)NN * 4, stream);
  hipMemsetAsync(cur, 0, (size_t)NN * 4, stream);
  hipMemsetAsync(d_out, 0, (size_t)NG * 20 * 4, stream);

  k_hist<<<(NT + 255) / 256, 256, 0, stream>>>(dst, cnt);
  k_scan<<<1, 1024, 0, stream>>>(cnt, offs);
  k_scatter<<<(NT + 255) / 256, 256, 0, stream>>>(src, dst, offs, cur, srt);

  // layer 0: FI=11, FO=192, H=3, C=64
  {
    dim3 g((NN + 63) / 64, 3);
    k_gemm_dual<<<g, 256, 0, stream>>>(x, NN, 11, 192, Wl[0], bl[0], Wr[0], br[0], xl, xr);
    k_gat<3, 64, true><<<(NN + 3) / 4, 256, 0, stream>>>(xl, xr, att[0], bb[0], offs, srt, hb);
  }
  // layers 1,2: FI=192, FO=192
  for (int li = 1; li <= 2; ++li) {
    dim3 g((NN + 63) / 64, 3);
    k_gemm_dual<<<g, 256, 0, stream>>>(hb, NN, 192, 192, Wl[li], bl[li], Wr[li], br[li], xl, xr);
    k_gat<3, 64, true><<<(NN + 3) / 4, 256, 0, stream>>>(xl, xr, att[li], bb[li], offs, srt, hb);
  }
  // layer 3: FI=192, FO=20, H=1, C=20, no relu
  {
    dim3 g((NN + 63) / 64, 1);
    k_gemm_dual<<<g, 256, 0, stream>>>(hb, NN, 192, 20, Wl[3], bl[3], Wr[3], br[3], xl, xr);
    k_gat<1, 20, false><<<(NN + 3) / 4, 256, 0, stream>>>(xl, xr, att[3], bb[3], offs, srt, hb);
  }
  k_pool<<<(NN * 20 + 255) / 256, 256, 0, stream>>>(hb, batch, (float*)d_out);
}

// Round 2
// 906.384 us; speedup vs baseline: 1.2274x; 1.2274x over previous
//
#include <hip/hip_runtime.h>

#define NN 50000
#define NE 800000
#define NT 850000   // NE + NN self loops
#define NG 512

// ---------------- edge bucket sort (by dst) ----------------

__global__ void k_hist(const int* __restrict__ dst, int* __restrict__ cnt) {
  int i = blockIdx.x * blockDim.x + threadIdx.x;
  if (i < NT) {
    int d = (i < NE) ? dst[i] : (i - NE);
    atomicAdd(&cnt[d], 1);
  }
}

// single-block scan: per-thread serial chunk + one 1024-wide scan
__global__ __launch_bounds__(1024)
void k_scan(const int* __restrict__ cnt, int* __restrict__ offs) {
  __shared__ int sh[1024];
  int tid = threadIdx.x;
  const int CH = (NN + 1023) / 1024;  // 49
  int base = tid * CH;
  int s = 0;
  for (int i = 0; i < CH; ++i) {
    int idx = base + i;
    if (idx < NN) s += cnt[idx];
  }
  sh[tid] = s;
  __syncthreads();
  for (int off = 1; off < 1024; off <<= 1) {
    int t = (tid >= off) ? sh[tid - off] : 0;
    __syncthreads();
    sh[tid] += t;
    __syncthreads();
  }
  int prefix = (tid > 0) ? sh[tid - 1] : 0;  // exclusive
  for (int i = 0; i < CH; ++i) {
    int idx = base + i;
    if (idx < NN) {
      offs[idx] = prefix;
      prefix += cnt[idx];
    }
  }
  if (tid == 1023) offs[NN] = sh[1023];
}

__global__ void k_scatter(const int* __restrict__ src, const int* __restrict__ dst,
                          const int* __restrict__ offs, int* __restrict__ cur,
                          int* __restrict__ srt) {
  int i = blockIdx.x * blockDim.x + threadIdx.x;
  if (i < NT) {
    int s, d;
    if (i < NE) { s = src[i]; d = dst[i]; }
    else        { s = d = i - NE; }
    int pos = offs[d] + atomicAdd(&cur[d], 1);
    srt[pos] = s;
  }
}

// ---------------- dual GEMM: C1 = A@W1^T + b1, C2 = A@W2^T + b2 ----------------
// A: [M,K] row-major; W: [FO,K] row-major; C: [M,FO]
// block tile 128x64, 256 threads, 8x4 micro-tile per thread, TK=16

__global__ __launch_bounds__(256)
void k_gemm_dual(const float* __restrict__ A, int M, int K, int FO,
                 const float* __restrict__ W1, const float* __restrict__ b1,
                 const float* __restrict__ W2, const float* __restrict__ b2,
                 float* __restrict__ C1, float* __restrict__ C2) {
  __shared__ float As[16][132];
  __shared__ float Bs1[16][68];
  __shared__ float Bs2[16][68];
  int tid = threadIdx.x;
  int tx = tid & 15, ty = tid >> 4;
  int mb = blockIdx.x * 128, nb = blockIdx.y * 64;
  bool k_vec = ((K & 3) == 0);
  float acc1[8][4] = {{0}}, acc2[8][4] = {{0}};
  for (int k0 = 0; k0 < K; k0 += 16) {
    // A tile: 128x16 = 512 float4, 2 per thread
#pragma unroll
    for (int q = 0; q < 2; ++q) {
      int f4 = tid + q * 256;
      int row = f4 >> 2, kq = (f4 & 3) * 4;
      float4 v = make_float4(0.f, 0.f, 0.f, 0.f);
      if (mb + row < M) {
        if (k_vec && k0 + kq + 3 < K) {
          v = *(const float4*)&A[(size_t)(mb + row) * K + k0 + kq];
        } else {
          float t[4];
#pragma unroll
          for (int i = 0; i < 4; ++i)
            t[i] = (k0 + kq + i < K) ? A[(size_t)(mb + row) * K + k0 + kq + i] : 0.f;
          v = make_float4(t[0], t[1], t[2], t[3]);
        }
      }
      As[kq + 0][row] = v.x; As[kq + 1][row] = v.y;
      As[kq + 2][row] = v.z; As[kq + 3][row] = v.w;
    }
    // B tiles: 64x16 = 256 float4 each, 1 per thread (dual)
    {
      int row = tid >> 2, kq = (tid & 3) * 4;
      float4 v1 = make_float4(0.f, 0.f, 0.f, 0.f), v2 = v1;
      if (nb + row < FO) {
        if (k_vec && k0 + kq + 3 < K) {
          v1 = *(const float4*)&W1[(size_t)(nb + row) * K + k0 + kq];
          v2 = *(const float4*)&W2[(size_t)(nb + row) * K + k0 + kq];
        } else {
          float t1[4], t2[4];
#pragma unroll
          for (int i = 0; i < 4; ++i) {
            bool ok = (k0 + kq + i < K);
            t1[i] = ok ? W1[(size_t)(nb + row) * K + k0 + kq + i] : 0.f;
            t2[i] = ok ? W2[(size_t)(nb + row) * K + k0 + kq + i] : 0.f;
          }
          v1 = make_float4(t1[0], t1[1], t1[2], t1[3]);
          v2 = make_float4(t2[0], t2[1], t2[2], t2[3]);
        }
      }
      Bs1[kq + 0][row] = v1.x; Bs1[kq + 1][row] = v1.y;
      Bs1[kq + 2][row] = v1.z; Bs1[kq + 3][row] = v1.w;
      Bs2[kq + 0][row] = v2.x; Bs2[kq + 1][row] = v2.y;
      Bs2[kq + 2][row] = v2.z; Bs2[kq + 3][row] = v2.w;
    }
    __syncthreads();
#pragma unroll
    for (int k = 0; k < 16; ++k) {
      float a[8], p[4], q[4];
#pragma unroll
      for (int i = 0; i < 8; ++i) a[i] = As[k][ty * 8 + i];
#pragma unroll
      for (int j = 0; j < 4; ++j) { p[j] = Bs1[k][tx * 4 + j]; q[j] = Bs2[k][tx * 4 + j]; }
#pragma unroll
      for (int i = 0; i < 8; ++i)
#pragma unroll
        for (int j = 0; j < 4; ++j) {
          acc1[i][j] = fmaf(a[i], p[j], acc1[i][j]);
          acc2[i][j] = fmaf(a[i], q[j], acc2[i][j]);
        }
    }
    __syncthreads();
  }
#pragma unroll
  for (int i = 0; i < 8; ++i) {
    int m = mb + ty * 8 + i;
    if (m >= M) continue;
#pragma unroll
    for (int j = 0; j < 4; ++j) {
      int n = nb + tx * 4 + j;
      if (n >= FO) continue;
      C1[(size_t)m * FO + n] = acc1[i][j] + b1[n];
      C2[(size_t)m * FO + n] = acc2[i][j] + b2[n];
    }
  }
}

// ---------------- fused GAT edge phase ----------------
// one wave per dst node; lane l = channel l of each head.
// DPP-based reduce (xor1,2,8 on VALU; xor4,16,32 via shfl), paired edges,
// merged 2-edge online softmax, 1-pair-ahead prefetch.

template <int CTRL>
__device__ __forceinline__ float dppf(float v) {
  return __int_as_float(__builtin_amdgcn_update_dpp(
      0, __float_as_int(v), CTRL, 0xF, 0xF, true));
}

template <int H, int C, bool RELU>
__global__ __launch_bounds__(256)
void k_gat(const float* __restrict__ xl, const float* __restrict__ xr,
           const float* __restrict__ att, const float* __restrict__ bias,
           const int* __restrict__ offs, const int* __restrict__ srt,
           float* __restrict__ out) {
  constexpr int FO = H * C;
  int wave = threadIdx.x >> 6;
  int lane = threadIdx.x & 63;
  int n = blockIdx.x * 4 + wave;
  if (n >= NN) return;
  bool act = (lane < C);
  float xr_v[H], att_v[H], m[H], d[H], acc[H];
#pragma unroll
  for (int h = 0; h < H; ++h) {
    int idx = h * C + lane;
    xr_v[h] = act ? xr[(size_t)n * FO + idx] : 0.f;
    att_v[h] = act ? att[idx] : 0.f;
    m[h] = -1e30f; d[h] = 0.f; acc[h] = 0.f;
  }
  int e0 = offs[n], e1 = offs[n + 1];

  float A0[H], A1[H];
  bool vA1 = false;
  auto ldp = [&](int j, float* X0, float* X1, bool& v1) {
    int s0 = srt[j];
    int j1 = (j + 1 < e1) ? j + 1 : j;
    v1 = (j + 1 < e1);
    int s1 = srt[j1];
#pragma unroll
    for (int h = 0; h < H; ++h) {
      X0[h] = act ? xl[(size_t)s0 * FO + h * C + lane] : 0.f;
      X1[h] = act ? xl[(size_t)s1 * FO + h * C + lane] : 0.f;
    }
  };

  if (e0 < e1) ldp(e0, A0, A1, vA1);
  for (int j = e0; j < e1; j += 2) {
    float B0[H], B1[H];
    bool vB1 = false;
    bool hn = (j + 2) < e1;
    if (hn) ldp(j + 2, B0, B1, vB1);

    float r[2 * H];
#pragma unroll
    for (int h = 0; h < H; ++h) {
      float t0 = A0[h] + xr_v[h];
      float t1 = A1[h] + xr_v[h];
      t0 = (t0 > 0.f) ? t0 : 0.2f * t0;
      t1 = (t1 > 0.f) ? t1 : 0.2f * t1;
      r[h] = t0 * att_v[h];
      r[H + h] = t1 * att_v[h];
    }
    // interleaved 64-lane reduction, all 2H values per step
#pragma unroll
    for (int v = 0; v < 2 * H; ++v) r[v] += dppf<0xB1>(r[v]);    // xor1 (quad_perm)
#pragma unroll
    for (int v = 0; v < 2 * H; ++v) r[v] += dppf<0x4E>(r[v]);    // xor2 (quad_perm)
#pragma unroll
    for (int v = 0; v < 2 * H; ++v) r[v] += __shfl_xor(r[v], 4, 64);
#pragma unroll
    for (int v = 0; v < 2 * H; ++v) r[v] += dppf<0x128>(r[v]);   // xor8 (row_ror:8)
#pragma unroll
    for (int v = 0; v < 2 * H; ++v) r[v] += __shfl_xor(r[v], 16, 64);
#pragma unroll
    for (int v = 0; v < 2 * H; ++v) r[v] += __shfl_xor(r[v], 32, 64);

#pragma unroll
    for (int h = 0; h < H; ++h) {
      float ea = r[h];
      float eb = vA1 ? r[H + h] : -1e30f;
      float nm = fmaxf(fmaxf(m[h], ea), eb);
      float sc = __expf(m[h] - nm);
      float p0 = __expf(ea - nm);
      float p1 = __expf(eb - nm);
      d[h] = fmaf(d[h], sc, p0 + p1);
      acc[h] = fmaf(acc[h], sc, fmaf(p0, A0[h], p1 * A1[h]));
      m[h] = nm;
    }
    if (hn) {
#pragma unroll
      for (int h = 0; h < H; ++h) { A0[h] = B0[h]; A1[h] = B1[h]; }
      vA1 = vB1;
    }
  }
#pragma unroll
  for (int h = 0; h < H; ++h) {
    if (act) {
      float v = acc[h] / d[h] + bias[h * C + lane];
      if (RELU) v = fmaxf(v, 0.f);
      out[(size_t)n * FO + h * C + lane] = v;
    }
  }
}

// ---------------- global add pool ----------------

__global__ void k_pool(const float* __restrict__ h, const int* __restrict__ batch,
                       float* __restrict__ out) {
  int i = blockIdx.x * blockDim.x + threadIdx.x;
  if (i < NN * 20) {
    int n = i / 20, k = i % 20;
    atomicAdd(&out[batch[n] * 20 + k], h[(size_t)n * 20 + k]);
  }
}

// ---------------- launch ----------------

extern "C" void kernel_launch(void* const* d_in, const int* in_sizes, int n_in,
                              void* d_out, int out_size, void* d_ws, size_t ws_size,
                              hipStream_t stream) {
  const float* x = (const float*)d_in[0];
  const int* src = (const int*)d_in[1];
  const int* dst = src + NE;
  const int* batch = (const int*)d_in[2];
  const float *Wl[4], *bl[4], *Wr[4], *br[4], *att[4], *bb[4];
  for (int li = 0; li < 4; ++li) {
    Wl[li]  = (const float*)d_in[3 + li * 6 + 0];
    bl[li]  = (const float*)d_in[3 + li * 6 + 1];
    Wr[li]  = (const float*)d_in[3 + li * 6 + 2];
    br[li]  = (const float*)d_in[3 + li * 6 + 3];
    att[li] = (const float*)d_in[3 + li * 6 + 4];
    bb[li]  = (const float*)d_in[3 + li * 6 + 5];
  }

  char* p = (char*)d_ws;
  auto alloc = [&](size_t bytes) {
    char* r = p;
    p += (bytes + 255) & ~(size_t)255;
    return r;
  };
  float* xl  = (float*)alloc((size_t)NN * 192 * 4);
  float* xr  = (float*)alloc((size_t)NN * 192 * 4);
  float* hb  = (float*)alloc((size_t)NN * 192 * 4);
  int* srt   = (int*)alloc((size_t)NT * 4);
  int* offs  = (int*)alloc((size_t)(NN + 1) * 4);
  int* cnt   = (int*)alloc((size_t)NN * 4);
  int* cur   = (int*)alloc((size_t)NN * 4);

  hipMemsetAsync(cnt, 0, (size_t)NN * 4, stream);
  hipMemsetAsync(cur, 0, (size_t)NN * 4, stream);
  hipMemsetAsync(d_out, 0, (size_t)NG * 20 * 4, stream);

  k_hist<<<(NT + 255) / 256, 256, 0, stream>>>(dst, cnt);
  k_scan<<<1, 1024, 0, stream>>>(cnt, offs);
  k_scatter<<<(NT + 255) / 256, 256, 0, stream>>>(src, dst, offs, cur, srt);

  // layer 0: FI=11, FO=192, H=3, C=64
  {
    dim3 g((NN + 127) / 128, 3);
    k_gemm_dual<<<g, 256, 0, stream>>>(x, NN, 11, 192, Wl[0], bl[0], Wr[0], br[0], xl, xr);
    k_gat<3, 64, true><<<(NN + 3) / 4, 256, 0, stream>>>(xl, xr, att[0], bb[0], offs, srt, hb);
  }
  // layers 1,2: FI=192, FO=192
  for (int li = 1; li <= 2; ++li) {
    dim3 g((NN + 127) / 128, 3);
    k_gemm_dual<<<g, 256, 0, stream>>>(hb, NN, 192, 192, Wl[li], bl[li], Wr[li], br[li], xl, xr);
    k_gat<3, 64, true><<<(NN + 3) / 4, 256, 0, stream>>>(xl, xr, att[li], bb[li], offs, srt, hb);
  }
  // layer 3: FI=192, FO=20, H=1, C=20, no relu
  {
    dim3 g((NN + 127) / 128, 1);
    k_gemm_dual<<<g, 256, 0, stream>>>(hb, NN, 192, 20, Wl[3], bl[3], Wr[3], br[3], xl, xr);
    k_gat<1, 20, false><<<(NN + 3) / 4, 256, 0, stream>>>(xl, xr, att[3], bb[3], offs, srt, hb);
  }
  k_pool<<<(NN * 20 + 255) / 256, 256, 0, stream>>>(hb, batch, (float*)d_out);
}

// Round 3
// 862.438 us; speedup vs baseline: 1.2900x; 1.0510x over previous
//
#include <hip/hip_runtime.h>

#define NN 50000
#define NE 800000
#define NT 850000   // NE + NN self loops
#define NG 512

// ==================== reduction / math helpers ====================

template <int CTRL>
__device__ __forceinline__ float dpp_add(float x) {
  int y = __builtin_amdgcn_update_dpp(0, __float_as_int(x), CTRL, 0xF, 0xF, true);
  return x + __int_as_float(y);
}

// full 64-lane sum, broadcast to all lanes
__device__ __forceinline__ float wave_sum(float x) {
  x = dpp_add<0xB1>(x);    // quad_perm [1,0,3,2]  (xor1)
  x = dpp_add<0x4E>(x);    // quad_perm [2,3,0,1]  (xor2)
  x = dpp_add<0x124>(x);   // row_ror:4
  x = dpp_add<0x128>(x);   // row_ror:8
  x = x + __int_as_float(__builtin_amdgcn_ds_swizzle(__float_as_int(x), 0x401F)); // xor16
  auto p = __builtin_amdgcn_permlane32_swap(__float_as_uint(x), __float_as_uint(x), false, false);
  return __uint_as_float(p[0]) + __uint_as_float(p[1]);   // + xor32
}

__device__ __forceinline__ float exp2_fast(float x) {
#if __has_builtin(__builtin_amdgcn_exp2f)
  return __builtin_amdgcn_exp2f(x);
#else
  return exp2f(x);
#endif
}

__device__ __forceinline__ float lrelu(float t) { return fmaxf(t, 0.2f * t); }

// packed f32 FMA: d += a.{lo or hi broadcast} * b (per-component)
__device__ __forceinline__ void pk_l(float2& d, float2 a, float2 b) {
  asm("v_pk_fma_f32 %0, %1, %2, %0 op_sel_hi:[0,1,1]" : "+v"(d) : "v"(a), "v"(b));
}
__device__ __forceinline__ void pk_h(float2& d, float2 a, float2 b) {
  asm("v_pk_fma_f32 %0, %1, %2, %0 op_sel:[1,0,0]" : "+v"(d) : "v"(a), "v"(b));
}

// ==================== edge bucket sort (by dst) ====================

__global__ void k_hist(const int* __restrict__ dst, int* __restrict__ cnt) {
  int i = blockIdx.x * blockDim.x + threadIdx.x;
  if (i < NT) {
    int d = (i < NE) ? dst[i] : (i - NE);
    atomicAdd(&cnt[d], 1);
  }
}

__global__ __launch_bounds__(1024)
void k_scan(const int* __restrict__ cnt, int* __restrict__ offs) {
  __shared__ int sh[1024];
  int tid = threadIdx.x;
  const int CH = (NN + 1023) / 1024;
  int base = tid * CH;
  int s = 0;
  for (int i = 0; i < CH; ++i) {
    int idx = base + i;
    if (idx < NN) s += cnt[idx];
  }
  sh[tid] = s;
  __syncthreads();
  for (int off = 1; off < 1024; off <<= 1) {
    int t = (tid >= off) ? sh[tid - off] : 0;
    __syncthreads();
    sh[tid] += t;
    __syncthreads();
  }
  int prefix = (tid > 0) ? sh[tid - 1] : 0;
  for (int i = 0; i < CH; ++i) {
    int idx = base + i;
    if (idx < NN) {
      offs[idx] = prefix;
      prefix += cnt[idx];
    }
  }
  if (tid == 1023) offs[NN] = sh[1023];
}

__global__ void k_scatter(const int* __restrict__ src, const int* __restrict__ dst,
                          const int* __restrict__ offs, int* __restrict__ cur,
                          int* __restrict__ srt) {
  int i = blockIdx.x * blockDim.x + threadIdx.x;
  if (i < NT) {
    int s, d;
    if (i < NE) { s = src[i]; d = dst[i]; }
    else        { s = d = i - NE; }
    int pos = offs[d] + atomicAdd(&cur[d], 1);
    srt[pos] = s;
  }
}

// ==================== dual GEMM with pk_fma + prefetch pipeline ====================
// C1 = A@W1^T + b1, C2 = A@W2^T + b2.  A:[M,K] W:[FO,K] row-major.
// tile 128x64, 256 threads, per-thread 8 rows x 4 cols, K-tile 32, reg-staged prefetch.

__global__ __launch_bounds__(256)
void k_gemm_dual(const float* __restrict__ A, int M, int K, int FO,
                 const float* __restrict__ W1, const float* __restrict__ bias1,
                 const float* __restrict__ W2, const float* __restrict__ bias2,
                 float* __restrict__ C1, float* __restrict__ C2) {
  __shared__ float As[32][132];
  __shared__ float Bs[2][32][68];
  int tid = threadIdx.x;
  int tx = tid & 15, ty = tid >> 4;
  int mb = blockIdx.x * 128, nb = blockIdx.y * 64;
  int nkt = (K + 31) >> 5;
  bool kvec = ((K & 3) == 0);

  float4 sa[4], sb[4];

  auto ldrowA = [&](int row, int k0, int kq) -> float4 {
    float4 v = make_float4(0.f, 0.f, 0.f, 0.f);
    if (mb + row < M) {
      if (kvec && k0 + kq + 3 < K) {
        v = *(const float4*)&A[(size_t)(mb + row) * K + k0 + kq];
      } else {
        float t[4];
#pragma unroll
        for (int i = 0; i < 4; ++i)
          t[i] = (k0 + kq + i < K) ? A[(size_t)(mb + row) * K + k0 + kq + i] : 0.f;
        v = make_float4(t[0], t[1], t[2], t[3]);
      }
    }
    return v;
  };
  auto ldrowW = [&](const float* W, int row, int k0, int kq) -> float4 {
    float4 v = make_float4(0.f, 0.f, 0.f, 0.f);
    if (nb + row < FO) {
      if (kvec && k0 + kq + 3 < K) {
        v = *(const float4*)&W[(size_t)(nb + row) * K + k0 + kq];
      } else {
        float t[4];
#pragma unroll
        for (int i = 0; i < 4; ++i)
          t[i] = (k0 + kq + i < K) ? W[(size_t)(nb + row) * K + k0 + kq + i] : 0.f;
        v = make_float4(t[0], t[1], t[2], t[3]);
      }
    }
    return v;
  };

  auto loadg = [&](int kt) {
    int k0 = kt * 32;
#pragma unroll
    for (int q = 0; q < 4; ++q) {
      int f4 = q * 256 + tid;
      sa[q] = ldrowA(f4 >> 3, k0, (f4 & 7) * 4);
    }
#pragma unroll
    for (int q = 0; q < 2; ++q) {
      int f4 = q * 256 + tid;
      sb[q]     = ldrowW(W1, f4 >> 3, k0, (f4 & 7) * 4);
      sb[2 + q] = ldrowW(W2, f4 >> 3, k0, (f4 & 7) * 4);
    }
  };
  auto store_lds = [&]() {
#pragma unroll
    for (int q = 0; q < 4; ++q) {
      int f4 = q * 256 + tid;
      int row = f4 >> 3, kq = (f4 & 7) * 4;
      As[kq + 0][row] = sa[q].x; As[kq + 1][row] = sa[q].y;
      As[kq + 2][row] = sa[q].z; As[kq + 3][row] = sa[q].w;
    }
#pragma unroll
    for (int q = 0; q < 2; ++q) {
      int f4 = q * 256 + tid;
      int row = f4 >> 3, kq = (f4 & 7) * 4;
      Bs[0][kq + 0][row] = sb[q].x; Bs[0][kq + 1][row] = sb[q].y;
      Bs[0][kq + 2][row] = sb[q].z; Bs[0][kq + 3][row] = sb[q].w;
      Bs[1][kq + 0][row] = sb[2 + q].x; Bs[1][kq + 1][row] = sb[2 + q].y;
      Bs[1][kq + 2][row] = sb[2 + q].z; Bs[1][kq + 3][row] = sb[2 + q].w;
    }
  };

  float2 c1[8][2], c2[8][2];
#pragma unroll
  for (int r = 0; r < 8; ++r)
#pragma unroll
    for (int j = 0; j < 2; ++j) {
      c1[r][j] = make_float2(0.f, 0.f);
      c2[r][j] = make_float2(0.f, 0.f);
    }

  loadg(0);
  for (int t = 0; t < nkt; ++t) {
    __syncthreads();
    store_lds();
    __syncthreads();
    if (t + 1 < nkt) loadg(t + 1);
#pragma unroll
    for (int k = 0; k < 32; ++k) {
      float2 a01 = *(const float2*)&As[k][ty * 8 + 0];
      float2 a23 = *(const float2*)&As[k][ty * 8 + 2];
      float2 a45 = *(const float2*)&As[k][ty * 8 + 4];
      float2 a67 = *(const float2*)&As[k][ty * 8 + 6];
      float2 f1a = *(const float2*)&Bs[0][k][tx * 4 + 0];
      float2 f1b = *(const float2*)&Bs[0][k][tx * 4 + 2];
      float2 f2a = *(const float2*)&Bs[1][k][tx * 4 + 0];
      float2 f2b = *(const float2*)&Bs[1][k][tx * 4 + 2];
#define PKROW(rp, a)                                                       \
      pk_l(c1[2 * rp + 0][0], a, f1a); pk_l(c1[2 * rp + 0][1], a, f1b);    \
      pk_h(c1[2 * rp + 1][0], a, f1a); pk_h(c1[2 * rp + 1][1], a, f1b);    \
      pk_l(c2[2 * rp + 0][0], a, f2a); pk_l(c2[2 * rp + 0][1], a, f2b);    \
      pk_h(c2[2 * rp + 1][0], a, f2a); pk_h(c2[2 * rp + 1][1], a, f2b);
      PKROW(0, a01) PKROW(1, a23) PKROW(2, a45) PKROW(3, a67)
#undef PKROW
    }
  }

#pragma unroll
  for (int r = 0; r < 8; ++r) {
    int m = mb + ty * 8 + r;
    if (m >= M) continue;
#pragma unroll
    for (int jp = 0; jp < 2; ++jp) {
      int col = nb + tx * 4 + jp * 2;
      if (col >= FO) continue;
      float2 bb1 = *(const float2*)&bias1[col];
      float2 bb2 = *(const float2*)&bias2[col];
      *(float2*)&C1[(size_t)m * FO + col] = make_float2(c1[r][jp].x + bb1.x, c1[r][jp].y + bb1.y);
      *(float2*)&C2[(size_t)m * FO + col] = make_float2(c2[r][jp].x + bb2.x, c2[r][jp].y + bb2.y);
    }
  }
}

// ==================== GAT edge phase, H=3 C=64: one node per 64-thread block ====================

#define LDX(s, X0, X1, X2) { int off_ = (s) * 192 + lane; \
  X0 = xl[off_]; X1 = xl[off_ + 64]; X2 = xl[off_ + 128]; }

__global__ __launch_bounds__(64)
void k_gat3(const float* __restrict__ xl, const float* __restrict__ xr,
            const float* __restrict__ att, const float* __restrict__ bias,
            const int* __restrict__ offs, const int* __restrict__ srt,
            float* __restrict__ out, int relu) {
  const float L2E = 1.4426950408889634f;
  int lane = threadIdx.x;
  int n = blockIdx.x;
  float xr0 = xr[n * 192 + lane], xr1 = xr[n * 192 + 64 + lane], xr2 = xr[n * 192 + 128 + lane];
  float at0 = att[lane] * L2E, at1 = att[64 + lane] * L2E, at2 = att[128 + lane] * L2E;
  float m0 = -1e30f, m1 = -1e30f, m2 = -1e30f;
  float d0 = 0.f, d1 = 0.f, d2 = 0.f;
  float a0 = 0.f, a1 = 0.f, a2 = 0.f;
  int e0 = offs[n], e1 = offs[n + 1];

  bool vA1 = (e0 + 1 < e1);
  int sA0 = srt[e0];
  int sA1 = vA1 ? srt[e0 + 1] : sA0;
  float XA0, XA1, XA2, XB0, XB1, XB2;
  LDX(sA0, XA0, XA1, XA2);
  LDX(sA1, XB0, XB1, XB2);

  for (int j = e0; j < e1; j += 2) {
    bool hn = (j + 2) < e1;
    bool vC1 = false;
    float YA0 = 0.f, YA1 = 0.f, YA2 = 0.f, YB0 = 0.f, YB1 = 0.f, YB2 = 0.f;
    if (hn) {
      int sC0 = srt[j + 2];
      vC1 = (j + 3 < e1);
      int sC1 = vC1 ? srt[j + 3] : sC0;
      LDX(sC0, YA0, YA1, YA2);
      LDX(sC1, YB0, YB1, YB2);
    }
    float r0 = lrelu(XA0 + xr0) * at0;
    float r1 = lrelu(XA1 + xr1) * at1;
    float r2 = lrelu(XA2 + xr2) * at2;
    float r3 = lrelu(XB0 + xr0) * at0;
    float r4 = lrelu(XB1 + xr1) * at1;
    float r5 = lrelu(XB2 + xr2) * at2;
    r0 = wave_sum(r0); r1 = wave_sum(r1); r2 = wave_sum(r2);
    r3 = wave_sum(r3); r4 = wave_sum(r4); r5 = wave_sum(r5);

    float eb0 = vA1 ? r3 : -1e30f;
    float eb1 = vA1 ? r4 : -1e30f;
    float eb2 = vA1 ? r5 : -1e30f;
    float pm0 = fmaxf(r0, eb0), pm1 = fmaxf(r1, eb1), pm2 = fmaxf(r2, eb2);
    float g = fmaxf(fmaxf(pm0 - m0, pm1 - m1), pm2 - m2);
    if (g > 11.0f) {   // rare rescale (defer-max); log2 domain
      float nm0 = fmaxf(m0, pm0), nm1 = fmaxf(m1, pm1), nm2 = fmaxf(m2, pm2);
      float s0 = exp2_fast(m0 - nm0), s1 = exp2_fast(m1 - nm1), s2 = exp2_fast(m2 - nm2);
      d0 *= s0; a0 *= s0; m0 = nm0;
      d1 *= s1; a1 *= s1; m1 = nm1;
      d2 *= s2; a2 *= s2; m2 = nm2;
    }
    float p00 = exp2_fast(r0 - m0), p10 = exp2_fast(eb0 - m0);
    float p01 = exp2_fast(r1 - m1), p11 = exp2_fast(eb1 - m1);
    float p02 = exp2_fast(r2 - m2), p12 = exp2_fast(eb2 - m2);
    d0 += p00 + p10;
    d1 += p01 + p11;
    d2 += p02 + p12;
    a0 = fmaf(p00, XA0, fmaf(p10, XB0, a0));
    a1 = fmaf(p01, XA1, fmaf(p11, XB1, a1));
    a2 = fmaf(p02, XA2, fmaf(p12, XB2, a2));
    if (hn) {
      XA0 = YA0; XA1 = YA1; XA2 = YA2;
      XB0 = YB0; XB1 = YB1; XB2 = YB2;
      vA1 = vC1;
    }
  }
  float v0 = a0 / d0 + bias[lane];
  float v1 = a1 / d1 + bias[64 + lane];
  float v2 = a2 / d2 + bias[128 + lane];
  if (relu) { v0 = fmaxf(v0, 0.f); v1 = fmaxf(v1, 0.f); v2 = fmaxf(v2, 0.f); }
  out[n * 192 + lane] = v0;
  out[n * 192 + 64 + lane] = v1;
  out[n * 192 + 128 + lane] = v2;
}

// ==================== GAT layer 3 (H=1, C=20) fused with global_add_pool ====================

__global__ __launch_bounds__(64)
void k_gat1(const float* __restrict__ xl, const float* __restrict__ xr,
            const float* __restrict__ att, const float* __restrict__ bias,
            const int* __restrict__ offs, const int* __restrict__ srt,
            const int* __restrict__ batch, float* __restrict__ gout) {
  const float L2E = 1.4426950408889634f;
  int lane = threadIdx.x;
  int n = blockIdx.x;
  int ll = (lane < 20) ? lane : 0;
  float xrv = xr[n * 20 + ll];
  float ats = (lane < 20) ? att[lane] * L2E : 0.f;
  float m = -1e30f, d = 0.f, acc = 0.f;
  int e0 = offs[n], e1 = offs[n + 1];

  bool vA1 = (e0 + 1 < e1);
  int sA0 = srt[e0];
  int sA1 = vA1 ? srt[e0 + 1] : sA0;
  float XA = xl[sA0 * 20 + ll];
  float XB = xl[sA1 * 20 + ll];

  for (int j = e0; j < e1; j += 2) {
    bool hn = (j + 2) < e1;
    bool vC1 = false;
    float YA = 0.f, YB = 0.f;
    if (hn) {
      int sC0 = srt[j + 2];
      vC1 = (j + 3 < e1);
      int sC1 = vC1 ? srt[j + 3] : sC0;
      YA = xl[sC0 * 20 + ll];
      YB = xl[sC1 * 20 + ll];
    }
    float r0 = lrelu(XA + xrv) * ats;
    float r1 = lrelu(XB + xrv) * ats;
    r0 = wave_sum(r0);
    r1 = wave_sum(r1);
    float eb = vA1 ? r1 : -1e30f;
    float pm = fmaxf(r0, eb);
    if (pm - m > 11.0f) {
      float nm = fmaxf(m, pm);
      float s = exp2_fast(m - nm);
      d *= s; acc *= s; m = nm;
    }
    float p0 = exp2_fast(r0 - m), p1 = exp2_fast(eb - m);
    d += p0 + p1;
    acc = fmaf(p0, XA, fmaf(p1, XB, acc));
    if (hn) { XA = YA; XB = YB; vA1 = vC1; }
  }
  if (lane < 20) {
    float v = acc / d + bias[lane];
    atomicAdd(&gout[batch[n] * 20 + lane], v);
  }
}

// ==================== launch ====================

extern "C" void kernel_launch(void* const* d_in, const int* in_sizes, int n_in,
                              void* d_out, int out_size, void* d_ws, size_t ws_size,
                              hipStream_t stream) {
  const float* x = (const float*)d_in[0];
  const int* src = (const int*)d_in[1];
  const int* dst = src + NE;
  const int* batch = (const int*)d_in[2];
  const float *Wl[4], *bl[4], *Wr[4], *br[4], *att[4], *bb[4];
  for (int li = 0; li < 4; ++li) {
    Wl[li]  = (const float*)d_in[3 + li * 6 + 0];
    bl[li]  = (const float*)d_in[3 + li * 6 + 1];
    Wr[li]  = (const float*)d_in[3 + li * 6 + 2];
    br[li]  = (const float*)d_in[3 + li * 6 + 3];
    att[li] = (const float*)d_in[3 + li * 6 + 4];
    bb[li]  = (const float*)d_in[3 + li * 6 + 5];
  }

  char* p = (char*)d_ws;
  auto alloc = [&](size_t bytes) {
    char* r = p;
    p += (bytes + 255) & ~(size_t)255;
    return r;
  };
  float* xl  = (float*)alloc((size_t)NN * 192 * 4);
  float* xr  = (float*)alloc((size_t)NN * 192 * 4);
  float* hb  = (float*)alloc((size_t)NN * 192 * 4);
  int* srt   = (int*)alloc((size_t)NT * 4);
  int* offs  = (int*)alloc((size_t)(NN + 1) * 4);
  int* cnt   = (int*)alloc((size_t)NN * 4);
  int* cur   = (int*)alloc((size_t)NN * 4);

  hipMemsetAsync(cnt, 0, (size_t)NN * 4, stream);
  hipMemsetAsync(cur, 0, (size_t)NN * 4, stream);
  hipMemsetAsync(d_out, 0, (size_t)NG * 20 * 4, stream);

  k_hist<<<(NT + 255) / 256, 256, 0, stream>>>(dst, cnt);
  k_scan<<<1, 1024, 0, stream>>>(cnt, offs);
  k_scatter<<<(NT + 255) / 256, 256, 0, stream>>>(src, dst, offs, cur, srt);

  // layer 0: FI=11, FO=192
  {
    dim3 g((NN + 127) / 128, 3);
    k_gemm_dual<<<g, 256, 0, stream>>>(x, NN, 11, 192, Wl[0], bl[0], Wr[0], br[0], xl, xr);
    k_gat3<<<NN, 64, 0, stream>>>(xl, xr, att[0], bb[0], offs, srt, hb, 1);
  }
  // layers 1,2: FI=192, FO=192
  for (int li = 1; li <= 2; ++li) {
    dim3 g((NN + 127) / 128, 3);
    k_gemm_dual<<<g, 256, 0, stream>>>(hb, NN, 192, 192, Wl[li], bl[li], Wr[li], br[li], xl, xr);
    k_gat3<<<NN, 64, 0, stream>>>(xl, xr, att[li], bb[li], offs, srt, hb, 1);
  }
  // layer 3: FI=192, FO=20, fused pool
  {
    dim3 g((NN + 127) / 128, 1);
    k_gemm_dual<<<g, 256, 0, stream>>>(hb, NN, 192, 20, Wl[3], bl[3], Wr[3], br[3], xl, xr);
    k_gat1<<<NN, 64, 0, stream>>>(xl, xr, att[3], bb[3], offs, srt, batch, (float*)d_out);
  }
}